// Round 1
// baseline (417.390 us; speedup 1.0000x reference)
//
#include <hip/hip_runtime.h>
#include <hip/hip_bf16.h>

#define ETA_C  0.1f
#define BETA_C 0.05f
#define MU_C   0.05f
#define MINI_C 1e-6f

// ---------- DPP wave-64 sum: result broadcast to all lanes via SGPR ----------
template<int CTRL, int ROWMASK>
__device__ __forceinline__ float dpp_add(float x) {
  int v = __builtin_amdgcn_update_dpp(0, __float_as_int(x), CTRL, ROWMASK, 0xf, true);
  return x + __int_as_float(v);
}

__device__ __forceinline__ float wave_sum(float x) {
  x = dpp_add<0xB1,  0xF>(x);   // quad_perm [1,0,3,2]  (xor 1)
  x = dpp_add<0x4E,  0xF>(x);   // quad_perm [2,3,0,1]  (xor 2)
  x = dpp_add<0x141, 0xF>(x);   // row_half_mirror      (xor 4-ish)
  x = dpp_add<0x140, 0xF>(x);   // row_mirror           (xor 8-ish)
  x = dpp_add<0x142, 0xA>(x);   // row_bcast:15 -> rows 1,3
  x = dpp_add<0x143, 0xC>(x);   // row_bcast:31 -> rows 2,3; lane63 = total
  return __int_as_float(__builtin_amdgcn_readlane(__float_as_int(x), 63));
}

// ---------- kernel A: column sums over V of seeds / exp_s / exp_n ----------
__global__ __launch_bounds__(256) void sums_kernel(
    const float* __restrict__ seeds, const float* __restrict__ es,
    const float* __restrict__ en, float* __restrict__ sums,
    int V, int rows_per_block) {
  __shared__ float sh[192];
  int t = threadIdx.x;
  if (t < 192) sh[t] = 0.f;
  __syncthreads();
  int k = t & 63, w = t >> 6;
  int v0 = blockIdx.x * rows_per_block;
  int v1 = min(v0 + rows_per_block, V);
  float s0 = 0.f, s1 = 0.f, s2 = 0.f;
  for (int v = v0 + w; v < v1; v += 4) {
    int idx = (v << 6) + k;
    s0 += seeds[idx]; s1 += es[idx]; s2 += en[idx];
  }
  atomicAdd(&sh[k], s0);
  atomicAdd(&sh[64 + k], s1);
  atomicAdd(&sh[128 + k], s2);
  __syncthreads();
  if (t < 192) atomicAdd(&sums[t], sh[t]);
}

// ---------- kernel B: main per-(v) wave kernel, b-loop inside ----------
__global__ __launch_bounds__(1024) void main_kernel(
    const float* __restrict__ bow,   // (B=64, V)
    const float* __restrict__ seeds, // (V, 64)
    const float* __restrict__ exp_m, // (64, 64)
    const float* __restrict__ exp_s, // (V, 64)
    const float* __restrict__ exp_n, // (V, 64)
    const float* __restrict__ pi,    // (64)
    const float* __restrict__ sums,  // [S | exp_s_sum | exp_n_sum]
    float* __restrict__ out,
    float* __restrict__ wsm, float* __restrict__ wsg, float* __restrict__ wsq,
    int V, int useWs) {
  __shared__ float theta_lds[4096];  // exp_m + ETA
  __shared__ float accm_lds[4096];   // temp_exp_m block partial
  __shared__ float red_gsr[16 * 64];
  __shared__ float red_qz[16];

  int t = threadIdx.x;
#pragma unroll
  for (int i = 0; i < 4; i++) {
    theta_lds[t + i * 1024] = exp_m[t + i * 1024] + ETA_C;
    accm_lds[t + i * 1024] = 0.f;
  }
  __syncthreads();

  int lane = t & 63, w = t >> 6;
  int v = blockIdx.x * 16 + w;
  bool active = (v < V);

  float acc_n = 0.f, acc_s = 0.f, acc_g = 0.f, acc_q = 0.f;

  if (active) {
    int rbase = (v << 6) + lane;
    float seed = seeds[rbase];
    float es = exp_s[rbase];
    float en = exp_n[rbase];
    float pik = pi[lane];
    float Sk = sums[lane], essum = sums[64 + lane], ensum = sums[128 + lane];
    float inv_ds = __builtin_amdgcn_rcpf(MU_C * Sk + essum);
    float inv_dn = __builtin_amdgcn_rcpf(BETA_C * (float)V + ensum);
    float phi_s = (MU_C + es) * inv_ds;
    float phi_n = (BETA_C + en) * inv_dn;
    float a_ss = seed * phi_s * pik;
    float a_sr = seed * phi_n * (1.0f - pik);
    float a_rr = (1.0f - seed) * phi_n;
    bool is_seed = (__ballot(seed > 0.f) != 0ull);
    float omp = 1.0f - pik;

    float bowpre = bow[lane * V + v];  // lane indexes b
    unsigned long long m = __ballot(bowpre > 0.f);

    while (m) {
      int b = __builtin_ctzll(m);
      m &= (m - 1);
      float cb = __int_as_float(
          __builtin_amdgcn_readlane(__float_as_int(bowpre), b));
      float theta = theta_lds[(b << 6) + lane];
      float gss_u = theta * a_ss;
      float gsr_u = theta * a_sr;
      float grr_u = theta * a_rr;
      float ssum = wave_sum(gss_u + gsr_u);
      float rsum = wave_sum(grr_u);
      float inv_s = __builtin_amdgcn_rcpf(ssum + MINI_C);
      float inv_r = __builtin_amdgcn_rcpf(rsum + MINI_C);
      float gss = gss_u * inv_s;
      float gsr = gsr_u * inv_s;
      float grr = grr_u * inv_r;
      float gnr = gsr + grr;
      float gamma = is_seed ? fmaf(pik, gss, omp * gnr) : grr;
      acc_n = fmaf(gnr, cb, acc_n);
      acc_s = fmaf(gss, cb, acc_s);
      acc_g += gsr;
      acc_q = fmaf(gamma, __logf(gamma + MINI_C), acc_q);
      atomicAdd(&accm_lds[(b << 6) + lane], gamma * cb);
    }

    out[4096 + rbase] = acc_n;            // temp_exp_n
    out[4096 + V * 64 + rbase] = acc_s;   // temp_exp_s
  }

  red_gsr[(w << 6) | lane] = acc_g;
  float qz_w = wave_sum(acc_q);
  if (lane == 0) red_qz[w] = qz_w;
  __syncthreads();

  // flush temp_exp_m block partial
  if (useWs) {
#pragma unroll
    for (int i = 0; i < 4; i++)
      wsm[blockIdx.x * 4096 + t + i * 1024] = accm_lds[t + i * 1024];
  } else {
#pragma unroll
    for (int i = 0; i < 4; i++)
      atomicAdd(&out[t + i * 1024], accm_lds[t + i * 1024]);
  }

  if (w == 0) {
    int gsr_off = 4096 + 2 * V * 64;
    float g = 0.f;
#pragma unroll
    for (int j = 0; j < 16; j++) g += red_gsr[(j << 6) | lane];
    if (useWs) wsg[blockIdx.x * 64 + lane] = g;
    else atomicAdd(&out[gsr_off + lane], g);
    if (t == 0) {
      float q = 0.f;
#pragma unroll
      for (int j = 0; j < 16; j++) q += red_qz[j];
      if (useWs) wsq[blockIdx.x] = q;
      else atomicAdd(&out[gsr_off + 64], q);
    }
  }
}

// ---------- kernel C: reduce per-block partials ----------
__global__ __launch_bounds__(256) void reduce_kernel(
    const float* __restrict__ wsm, const float* __restrict__ wsg,
    const float* __restrict__ wsq, float* __restrict__ out,
    int NB, int V, int chunk) {
  if (blockIdx.x < 16) {
    int e = blockIdx.x * 256 + threadIdx.x;
    int j0 = blockIdx.y * chunk;
    int j1 = min(j0 + chunk, NB);
    float s = 0.f;
    for (int j = j0; j < j1; j++) s += wsm[j * 4096 + e];
    atomicAdd(&out[e], s);
  } else if (blockIdx.y == 0) {
    int t = threadIdx.x;
    int gsr_off = 4096 + 2 * V * 64;
    if (t < 64) {
      float s = 0.f;
      for (int j = 0; j < NB; j++) s += wsg[j * 64 + t];
      out[gsr_off + t] = s;
    } else if (t < 128) {
      int lane = t - 64;
      float s = 0.f;
      for (int j = lane; j < NB; j += 64) s += wsq[j];
      s = wave_sum(s);
      if (lane == 0) out[gsr_off + 64] = s;
    }
  }
}

extern "C" void kernel_launch(void* const* d_in, const int* in_sizes, int n_in,
                              void* d_out, int out_size, void* d_ws,
                              size_t ws_size, hipStream_t stream) {
  (void)n_in;
  const float* bow   = (const float*)d_in[0];
  const float* seeds = (const float*)d_in[1];
  const float* exp_m = (const float*)d_in[2];
  const float* exp_s = (const float*)d_in[3];
  const float* exp_n = (const float*)d_in[4];
  const float* pi    = (const float*)d_in[5];
  int K = in_sizes[5];          // 64
  int V = in_sizes[1] / K;      // 10000
  float* out = (float*)d_out;
  float* ws = (float*)d_ws;

  int NB = (V + 15) / 16;       // 625 blocks, 16 waves (one v each) per block
  size_t need = (size_t)(256 + (size_t)NB * 4096 + (size_t)NB * 64 + NB) * 4;
  int useWs = (ws_size >= need) ? 1 : 0;

  float* sums = ws;             // 192 floats (+pad)
  float* wsm = ws + 256;        // NB x 4096
  float* wsg = wsm + (size_t)NB * 4096;  // NB x 64
  float* wsq = wsg + (size_t)NB * 64;    // NB

  hipMemsetAsync(d_out, 0, (size_t)out_size * sizeof(float), stream);
  hipMemsetAsync(d_ws, 0, 768, stream);

  int rpb = (V + 99) / 100;
  sums_kernel<<<100, 256, 0, stream>>>(seeds, exp_s, exp_n, sums, V, rpb);
  main_kernel<<<NB, 1024, 0, stream>>>(bow, seeds, exp_m, exp_s, exp_n, pi,
                                       sums, out, wsm, wsg, wsq, V, useWs);
  if (useWs) {
    int chunk = (NB + 4) / 5;
    reduce_kernel<<<dim3(17, 5), 256, 0, stream>>>(wsm, wsg, wsq, out, NB, V,
                                                   chunk);
  }
}